// Round 1
// baseline (2935.865 us; speedup 1.0000x reference)
//
#include <hip/hip_runtime.h>
#include <math.h>

#define Bq 8
#define Tq 4096
#define Dq 512
#define Qn 4
#define Kk 1024
#define OWn 2048
#define NROWS (Bq*Tq)

#define QO_OFF (Bq*OWn*Dq)
#define IDX_OFF (QO_OFF + Bq*Tq*Dq)
#define LOSS_OFF (IDX_OFF + Qn*NROWS)

// ---------------- prep: codebook norms + zero loss acc ----------------
__global__ __launch_bounds__(256) void prep_kernel(const float* __restrict__ cb,
                                                   float* __restrict__ cbnorm,
                                                   float* __restrict__ loss_acc) {
  int wave = threadIdx.x >> 6, lane = threadIdx.x & 63;
  int row = blockIdx.x * 4 + wave;               // 0..4095 (Qn*Kk)
  const float4* c4 = (const float4*)(cb + (size_t)row * Dq);
  float s = 0.f;
#pragma unroll
  for (int i = 0; i < 2; ++i) {
    float4 v = c4[lane * 2 + i];
    s += v.x*v.x + v.y*v.y + v.z*v.z + v.w*v.w;
  }
#pragma unroll
  for (int off = 32; off; off >>= 1) s += __shfl_down(s, off);
  if (lane == 0) cbnorm[row] = s;
  if (blockIdx.x == 0 && threadIdx.x == 0) *loss_acc = 0.f;
}

// ---------------- one residual-VQ step: scores + argmin + update ----------------
// block: 256 threads, BM=64 rows, loops k-tiles of 128 (8 tiles), d-tiles of 32 (16)
__global__ __launch_bounds__(256) void vq_step(const float* __restrict__ x,
                                               const float* __restrict__ cbq,      // codebooks + qi*Kk*Dq
                                               const float* __restrict__ cbnorm_q, // ws norms + qi*Kk
                                               float* __restrict__ qo,             // quantized accum (d_out)
                                               float* __restrict__ idx_out,        // d_out idx region + qi*NROWS
                                               float* __restrict__ loss_acc,
                                               int first) {
  __shared__ float lds_cb[128 * 36];
  __shared__ float lds_r[64 * 36];
  __shared__ float redS[64 * 17];
  __shared__ int   redK[64 * 17];
  __shared__ int   lds_idx[64];
  __shared__ float lsum[4];

  const int tid = threadIdx.x;
  const int r = tid >> 4;     // 0..15 -> rows r+16m
  const int c = tid & 15;     // 0..15 -> k = c+16n within k-tile
  const int row0 = blockIdx.x * 64;

  float bestS[4];
  int bestK[4];
#pragma unroll
  for (int m = 0; m < 4; ++m) { bestS[m] = 3.4028235e38f; bestK[m] = 0; }

  for (int kt = 0; kt < 8; ++kt) {
    float acc[4][8];
#pragma unroll
    for (int m = 0; m < 4; ++m)
#pragma unroll
      for (int n = 0; n < 8; ++n) acc[m][n] = 0.f;

    for (int dt = 0; dt < 16; ++dt) {
      __syncthreads();
      // stage codebook tile: 128 rows x 32 d  (1024 float4 slots, 4/thread)
#pragma unroll
      for (int i = 0; i < 4; ++i) {
        int s = i * 256 + tid;
        int kr = s >> 3, c4 = s & 7;
        float4 v = *(const float4*)(cbq + (size_t)(kt * 128 + kr) * Dq + dt * 32 + c4 * 4);
        *(float4*)(lds_cb + kr * 36 + c4 * 4) = v;
      }
      // stage residual tile r = x - quant  (64 rows x 32 d, 512 slots, 2/thread)
#pragma unroll
      for (int i = 0; i < 2; ++i) {
        int s = i * 256 + tid;
        int rr = s >> 3, c4 = s & 7;
        size_t g = (size_t)(row0 + rr) * Dq + dt * 32 + c4 * 4;
        float4 xv = *(const float4*)(x + g);
        float4 rv;
        if (first) rv = xv;
        else {
          float4 qv = *(const float4*)(qo + g);
          rv.x = xv.x - qv.x; rv.y = xv.y - qv.y; rv.z = xv.z - qv.z; rv.w = xv.w - qv.w;
        }
        *(float4*)(lds_r + rr * 36 + c4 * 4) = rv;
      }
      __syncthreads();
#pragma unroll
      for (int d4 = 0; d4 < 8; ++d4) {
        float4 rv[4];
#pragma unroll
        for (int m = 0; m < 4; ++m)
          rv[m] = *(float4*)(lds_r + (r + 16 * m) * 36 + d4 * 4);
#pragma unroll
        for (int n = 0; n < 8; ++n) {
          float4 cv = *(float4*)(lds_cb + (c + 16 * n) * 36 + d4 * 4);
#pragma unroll
          for (int m = 0; m < 4; ++m) {
            acc[m][n] = fmaf(rv[m].x, cv.x, acc[m][n]);
            acc[m][n] = fmaf(rv[m].y, cv.y, acc[m][n]);
            acc[m][n] = fmaf(rv[m].z, cv.z, acc[m][n]);
            acc[m][n] = fmaf(rv[m].w, cv.w, acc[m][n]);
          }
        }
      }
    }
    // merge scores for this k-tile: score = ||cb||^2 - 2 r.cb   (k ascending per thread)
#pragma unroll
    for (int n = 0; n < 8; ++n) {
      int k = kt * 128 + c + 16 * n;
      float cn = cbnorm_q[k];
#pragma unroll
      for (int m = 0; m < 4; ++m) {
        float s = cn - 2.f * acc[m][n];
        if (s < bestS[m]) { bestS[m] = s; bestK[m] = k; }
      }
    }
  }

  __syncthreads();
#pragma unroll
  for (int m = 0; m < 4; ++m) {
    int row = r + 16 * m;
    redS[row * 17 + c] = bestS[m];
    redK[row * 17 + c] = bestK[m];
  }
  __syncthreads();
  if (tid < 64) {
    float bs = redS[tid * 17]; int bk = redK[tid * 17];
#pragma unroll
    for (int cc = 1; cc < 16; ++cc) {
      float s = redS[tid * 17 + cc]; int k = redK[tid * 17 + cc];
      if (s < bs || (s == bs && k < bk)) { bs = s; bk = k; }
    }
    lds_idx[tid] = bk;
    idx_out[row0 + tid] = (float)bk;
  }
  __syncthreads();

  // update: quant += cb[idx]; loss += sum((x - quant_new)^2)
  int urow = tid >> 2, l4 = tid & 3;
  int k = lds_idx[urow];
  size_t grow = (size_t)(row0 + urow) * Dq;
  const float4* cbrow = (const float4*)(cbq + (size_t)k * Dq);
  const float4* xrow  = (const float4*)(x + grow);
  float4* qrow = (float4*)(qo + grow);
  float lp = 0.f;
#pragma unroll 4
  for (int j = 0; j < 32; ++j) {
    int c4 = l4 + 4 * j;
    float4 cv = cbrow[c4];
    float4 qn;
    if (first) qn = cv;
    else {
      float4 qp = qrow[c4];
      qn.x = qp.x + cv.x; qn.y = qp.y + cv.y; qn.z = qp.z + cv.z; qn.w = qp.w + cv.w;
    }
    qrow[c4] = qn;
    float4 xv = xrow[c4];
    float a = xv.x - qn.x, b = xv.y - qn.y, d = xv.z - qn.z, e = xv.w - qn.w;
    lp += a*a + b*b + d*d + e*e;
  }
#pragma unroll
  for (int off = 32; off; off >>= 1) lp += __shfl_down(lp, off);
  if ((tid & 63) == 0) lsum[tid >> 6] = lp;
  __syncthreads();
  if (tid == 0) atomicAdd(loss_acc, lsum[0] + lsum[1] + lsum[2] + lsum[3]);
}

// ---------------- conv1d stride2 SAME + exact GELU ----------------
// grid: (co blocks 8, o blocks 32, batch 8); block 256; BM=64 positions, BN=64 co
__global__ __launch_bounds__(256) void conv_gelu(const float* __restrict__ qo,
                                                 const float* __restrict__ w,
                                                 float* __restrict__ y) {
  __shared__ float A[132 * 20];     // 131 input rows x 16 ci (pad 20)
  __shared__ float Wt[5 * 16 * 64]; // [kw][ci][co]
  const int tid = threadIdx.x;
  const int r = tid >> 4, c = tid & 15;
  const int co0 = blockIdx.x * 64, o0 = blockIdx.y * 64, n = blockIdx.z;

  float acc[4][4];
#pragma unroll
  for (int m = 0; m < 4; ++m)
#pragma unroll
    for (int j = 0; j < 4; ++j) acc[m][j] = 0.f;

  for (int dt = 0; dt < 32; ++dt) {
    __syncthreads();
    // stage input window: rows gi = 2*o0-1 .. 2*o0+129 (zero-padded), 16 ci
    for (int s = tid; s < 524; s += 256) {
      int row = s >> 2, c4 = s & 3;
      int gi = 2 * o0 - 1 + row;
      float4 v = {0.f, 0.f, 0.f, 0.f};
      if (gi >= 0 && gi < Tq)
        v = *(const float4*)(qo + (size_t)(n * Tq + gi) * Dq + dt * 16 + c4 * 4);
      *(float4*)(A + row * 20 + c4 * 4) = v;
    }
    // stage weights: [5][16][64], 1280 float4 slots, 5/thread
#pragma unroll
    for (int i = 0; i < 5; ++i) {
      int s = i * 256 + tid;
      int kw = s >> 8, rest = s & 255, ci = rest >> 4, c4 = rest & 15;
      float4 v = *(const float4*)(w + (size_t)(kw * Dq + dt * 16 + ci) * Dq + co0 + c4 * 4);
      *(float4*)(Wt + (kw * 16 + ci) * 64 + c4 * 4) = v;
    }
    __syncthreads();
#pragma unroll 4
    for (int ci = 0; ci < 16; ++ci) {
      float4 wv[5];
#pragma unroll
      for (int kw = 0; kw < 5; ++kw)
        wv[kw] = *(float4*)(Wt + (kw * 16 + ci) * 64 + c * 4);
#pragma unroll
      for (int m = 0; m < 4; ++m) {
        int p2 = 2 * (r + 16 * m);
#pragma unroll
        for (int kw = 0; kw < 5; ++kw) {
          float a = A[(p2 + kw) * 20 + ci];
          acc[m][0] = fmaf(a, wv[kw].x, acc[m][0]);
          acc[m][1] = fmaf(a, wv[kw].y, acc[m][1]);
          acc[m][2] = fmaf(a, wv[kw].z, acc[m][2]);
          acc[m][3] = fmaf(a, wv[kw].w, acc[m][3]);
        }
      }
    }
  }
#pragma unroll
  for (int m = 0; m < 4; ++m) {
    int p = o0 + r + 16 * m;
    float4 g;
    g.x = 0.5f * acc[m][0] * (1.f + erff(acc[m][0] * 0.70710678118654752f));
    g.y = 0.5f * acc[m][1] * (1.f + erff(acc[m][1] * 0.70710678118654752f));
    g.z = 0.5f * acc[m][2] * (1.f + erff(acc[m][2] * 0.70710678118654752f));
    g.w = 0.5f * acc[m][3] * (1.f + erff(acc[m][3] * 0.70710678118654752f));
    *(float4*)(y + (size_t)(n * OWn + p) * Dq + co0 + c * 4) = g;
  }
}

__global__ void loss_final(const float* __restrict__ loss_acc, float* __restrict__ out) {
  out[0] = 0.25f * loss_acc[0] / 16777216.0f;
}

extern "C" void kernel_launch(void* const* d_in, const int* in_sizes, int n_in,
                              void* d_out, int out_size, void* d_ws, size_t ws_size,
                              hipStream_t stream) {
  const float* x  = (const float*)d_in[0];
  const float* cb = (const float*)d_in[1];
  const float* w  = (const float*)d_in[2];
  float* out = (float*)d_out;
  float* y    = out;
  float* qo   = out + QO_OFF;
  float* idxo = out + IDX_OFF;
  float* losso = out + LOSS_OFF;
  float* cbnorm = (float*)d_ws;
  float* lacc = cbnorm + Qn * Kk;

  prep_kernel<<<1024, 256, 0, stream>>>(cb, cbnorm, lacc);
  for (int qi = 0; qi < Qn; ++qi)
    vq_step<<<512, 256, 0, stream>>>(x, cb + (size_t)qi * Kk * Dq, cbnorm + qi * Kk,
                                     qo, idxo + qi * NROWS, lacc, qi == 0);
  conv_gelu<<<dim3(8, 32, 8), 256, 0, stream>>>(qo, w, y);
  loss_final<<<1, 1, 0, stream>>>(lacc, losso);
}